// Round 4
// baseline (45.272 us; speedup 1.0000x reference)
//
#include <hip/hip_runtime.h>

// D-FINE post-processor: per-batch top-K over sigmoid(logits) flattened [Q*C].
// One block per batch, 1024 threads.
// Hot path (single HBM pass): burst-load whole batch (20 x float4/thread, fenced
// with sched_barrier so all loads stay in flight), collect candidates with
// logit > THR into LDS. Since {x > THR} is a prefix of the descending order,
// if K <= count <= CAP the top-K is contained; rank-select and emit.
// Fallback (any input where the bound check fails): exact 4096-bin histogram ->
// threshold bin -> gather -> same rank/emit. Never triggers on N(0,1) logits.
// Output (float32): labels [B*K] | boxes [B*K*4] | scores [B*K]

constexpr int   NT    = 1024;
constexpr int   UN    = 20;      // float4 loads per thread per super-iter (20480 >= 20000)
constexpr int   NBINS = 4096;
constexpr int   CAP   = 4096;
constexpr float THR   = 2.4f;    // static pre-filter on logits (fallback makes it safe)

__device__ __forceinline__ unsigned f2key(float f) {
    unsigned u = __float_as_uint(f);
    return (u & 0x80000000u) ? ~u : (u | 0x80000000u);
}
__device__ __forceinline__ float key2f(unsigned k) {
    unsigned u = (k & 0x80000000u) ? (k & 0x7FFFFFFFu) : ~k;
    return __uint_as_float(u);
}

__global__ __launch_bounds__(NT) void dfine_topk_kernel(
    const float* __restrict__ logits,   // [B, Q*C]
    const float* __restrict__ pboxes,   // [B, Q, 4]  (cx, cy, w, h)
    const float* __restrict__ sizes,    // [B, 2]
    float* __restrict__ out,            // labels | boxes | scores
    int B, int Q, int C, int K)
{
    const int b   = blockIdx.x;
    const int tid = threadIdx.x;
    const int N   = Q * C;
    const int N4  = N >> 2;             // N divisible by 4 (C=80)
    const float4* __restrict__ lg4 = reinterpret_cast<const float4*>(logits + (long long)b * N);

    __shared__ unsigned long long cand[CAP];   // 32 KB
    __shared__ unsigned hist[NBINS];           // 16 KB (fallback only)
    __shared__ unsigned partial[NT];           //  4 KB (fallback only)
    __shared__ unsigned candCount;
    __shared__ unsigned threshBin;
    __shared__ int fb;

    if (tid == 0) candCount = 0u;
    __syncthreads();

    // ---- Hot path: ONE streaming pass, deep burst, static pre-filter ----
    for (int s = 0; s < N4; s += UN * NT) {
        float4 v[UN];
        #pragma unroll
        for (int j = 0; j < UN; ++j) {
            int i4 = s + j * NT + tid;
            int c  = (i4 < N4) ? i4 : (N4 - 1);       // clamped load, predicated use
            v[j] = lg4[c];
        }
        __builtin_amdgcn_sched_barrier(0);            // keep all UN loads in flight
        #pragma unroll
        for (int j = 0; j < UN; ++j) {
            int i4 = s + j * NT + tid;
            if (i4 < N4) {
                unsigned base = (unsigned)(4 * i4);
                float x0 = v[j].x, x1 = v[j].y, x2 = v[j].z, x3 = v[j].w;
                if (x0 > THR) { unsigned p = atomicAdd(&candCount, 1u);
                    if (p < (unsigned)CAP) cand[p] = ((unsigned long long)f2key(x0) << 32) | (unsigned long long)(0xFFFFFFFFu - (base + 0)); }
                if (x1 > THR) { unsigned p = atomicAdd(&candCount, 1u);
                    if (p < (unsigned)CAP) cand[p] = ((unsigned long long)f2key(x1) << 32) | (unsigned long long)(0xFFFFFFFFu - (base + 1)); }
                if (x2 > THR) { unsigned p = atomicAdd(&candCount, 1u);
                    if (p < (unsigned)CAP) cand[p] = ((unsigned long long)f2key(x2) << 32) | (unsigned long long)(0xFFFFFFFFu - (base + 2)); }
                if (x3 > THR) { unsigned p = atomicAdd(&candCount, 1u);
                    if (p < (unsigned)CAP) cand[p] = ((unsigned long long)f2key(x3) << 32) | (unsigned long long)(0xFFFFFFFFu - (base + 3)); }
            }
        }
    }
    __syncthreads();

    // ---- Bound check: does {x > THR} provably contain the top-K and fit? ----
    if (tid == 0) fb = (candCount < (unsigned)K || candCount > (unsigned)CAP) ? 1 : 0;
    __syncthreads();

    if (fb) {
        // ---- Fallback: exact histogram selection (rare; correctness only) ----
        for (int i = tid; i < NBINS; i += NT) hist[i] = 0u;
        if (tid == 0) candCount = 0u;
        __syncthreads();
        const float* __restrict__ lg = logits + (long long)b * N;
        for (int i = tid; i < N; i += NT)
            atomicAdd(&hist[f2key(lg[i]) >> 20], 1u);
        __syncthreads();
        {   // hierarchical threshold find
            const int BPT = NBINS / NT;
            unsigned s = 0;
            #pragma unroll
            for (int m = 0; m < BPT; ++m) s += hist[tid * BPT + m];
            partial[tid] = s;
        }
        __syncthreads();
        if (tid < 64) {
            const int PPG = NT / 64;
            unsigned gs = 0;
            #pragma unroll
            for (int m = 0; m < PPG; ++m) gs += partial[tid * PPG + m];
            unsigned pre = gs;
            #pragma unroll
            for (int off = 1; off < 64; off <<= 1) {
                unsigned t = __shfl_up(pre, off);
                if (tid >= off) pre += t;
            }
            unsigned total = __shfl(pre, 63);
            unsigned suf   = total - (pre - gs);
            unsigned long long m1 = __ballot(suf >= (unsigned)K);
            int g = 63 - __clzll(m1);
            unsigned above = total - __shfl(pre, g);
            unsigned hv = hist[g * 64 + tid];
            unsigned pre2 = hv;
            #pragma unroll
            for (int off = 1; off < 64; off <<= 1) {
                unsigned t = __shfl_up(pre2, off);
                if (tid >= off) pre2 += t;
            }
            unsigned total2 = __shfl(pre2, 63);
            unsigned suf2   = above + total2 - (pre2 - hv);
            unsigned long long m2 = __ballot(suf2 >= (unsigned)K);
            int l2 = 63 - __clzll(m2);
            if (tid == 0) threshBin = (unsigned)(g * 64 + l2);
        }
        __syncthreads();
        const unsigned tb = threshBin;
        for (int i = tid; i < N; i += NT) {
            unsigned k = f2key(lg[i]);
            if ((k >> 20) >= tb) {
                unsigned p = atomicAdd(&candCount, 1u);
                if (p < (unsigned)CAP)
                    cand[p] = ((unsigned long long)k << 32) | (unsigned long long)(0xFFFFFFFFu - (unsigned)i);
            }
        }
        __syncthreads();
    }

    const int n = (int)min(candCount, (unsigned)CAP);

    // ---- Rank-based selection + emit ----
    const int BK = B * K;
    float* __restrict__ out_labels = out;
    float* __restrict__ out_boxes  = out + BK;
    float* __restrict__ out_scores = out + (long long)BK * 5;
    const float s0 = sizes[2 * b];
    const float s1 = sizes[2 * b + 1];

    for (int t = tid; t < n; t += NT) {
        unsigned long long my = cand[t];
        int r = 0;
        for (int j = 0; j < n; ++j) r += (cand[j] > my);   // packed keys unique
        if (r < K) {
            unsigned key = (unsigned)(my >> 32);
            unsigned idx = 0xFFFFFFFFu - (unsigned)(my & 0xFFFFFFFFull);
            float logit = key2f(key);
            float score = 1.0f / (1.0f + expf(-logit));
            int label = (int)(idx % (unsigned)C);
            int q     = (int)(idx / (unsigned)C);
            float4 bp = *reinterpret_cast<const float4*>(pboxes + ((long long)b * Q + q) * 4);
            int o = b * K + r;
            out_labels[o] = (float)label;
            out_scores[o] = score;
            float4 bb;
            bb.x = (bp.x - 0.5f * bp.z) * s0;
            bb.y = (bp.y - 0.5f * bp.w) * s1;
            bb.z = (bp.x + 0.5f * bp.z) * s0;
            bb.w = (bp.y + 0.5f * bp.w) * s1;
            *reinterpret_cast<float4*>(out_boxes + 4LL * o) = bb;
        }
    }
}

extern "C" void kernel_launch(void* const* d_in, const int* in_sizes, int n_in,
                              void* d_out, int out_size, void* d_ws, size_t ws_size,
                              hipStream_t stream) {
    const float* logits = (const float*)d_in[0];
    const float* pboxes = (const float*)d_in[1];
    const float* sizes  = (const float*)d_in[2];

    const int B = in_sizes[2] / 2;                 // 256
    const int Q = in_sizes[1] / (4 * B);           // 1000
    const int C = in_sizes[0] / (B * Q);           // 80
    const int K = out_size / (6 * B);              // 300

    dfine_topk_kernel<<<B, NT, 0, stream>>>(
        logits, pboxes, sizes, (float*)d_out, B, Q, C, K);
}